// Round 2
// baseline (754.984 us; speedup 1.0000x reference)
//
#include <hip/hip_runtime.h>
#include <math.h>

// MDTA fused: pass1 (qk conv + Gram), attn (softmax + fold w_out), pass2 (v conv * illu @ M)
// Shapes: B=4, DIM=64, H=W=256, HEADS=4, DHEAD=16, INNER=64, L=65536
// (Resubmit of round-1 kernel: round-1 bench died to container infra, no signal.)
#define NB 4
#define NC 64
#define NH 256
#define NW 256
#define NL (NH * NW)
#define NHEADS 4

// ws layout (floats): gram[4][4][288] at 0 (4608 floats); Mt[4][64][64] at 8192 (16384 floats)
#define GRAM_FLOATS 4608
#define MT_OFF 8192

// ---------------------------------------------------------------------------
// Pass 1: for each 16x16 tile, compute pre-dw q,k (1x1 conv) on 18x18 halo,
// dw 3x3, then accumulate per-head Gram matrix + squared norms via atomics.
// ---------------------------------------------------------------------------
__global__ __launch_bounds__(256, 2) void pass1_kernel(
    const float* __restrict__ x, const float* __restrict__ wqkv,
    const float* __restrict__ wdw, float* __restrict__ gram)
{
    __shared__ float predw[32][328];  // [chan][halo pixel], pad 324->328
    __shared__ float qk[32][262];     // rows 0..15 q, 16..31 k; stride 262 (conflict-spread)

    const int bid = blockIdx.x;
    const int b = bid >> 8;
    const int tile = bid & 255;
    const int y0 = (tile >> 4) << 4;
    const int x0 = (tile & 15) << 4;
    const int tid = threadIdx.x;
    const int iy = tid >> 4, ix = tid & 15;

    for (int n = 0; n < NHEADS; ++n) {
        // Phase A: pointwise conv for this head's 16 q + 16 k channels over halo
        for (int task = tid; task < 324; task += 256) {
            const int hy = task / 18;
            const int hx = task - hy * 18;
            const int py = y0 + hy - 1;
            const int px = x0 + hx - 1;
            const bool valid = (py >= 0) && (py < NH) && (px >= 0) && (px < NW);
            const float* xp = x + (size_t)b * (NC * NL) + py * NW + px;
            float xr[NC];
            #pragma unroll
            for (int c = 0; c < NC; ++c)
                xr[c] = valid ? xp[(size_t)c * NL] : 0.0f;
            for (int j = 0; j < 16; ++j) {
                const float* wq = wqkv + (n * 16 + j) * NC;        // q channel row
                const float* wk = wqkv + (64 + n * 16 + j) * NC;   // k channel row
                float aq = 0.f, ak = 0.f;
                #pragma unroll
                for (int c = 0; c < NC; ++c) {
                    aq = fmaf(wq[c], xr[c], aq);
                    ak = fmaf(wk[c], xr[c], ak);
                }
                predw[j][task] = aq;
                predw[16 + j][task] = ak;
            }
        }
        __syncthreads();

        // Phase B: depthwise 3x3 (SAME, zero pad handled by predw=0 on OOB halo)
        {
            const int hp = (iy + 1) * 18 + (ix + 1);
            #pragma unroll
            for (int j = 0; j < 32; ++j) {
                const int ch = (j < 16) ? (n * 16 + j) : (64 + n * 16 + (j - 16));
                const float* wd = wdw + ch * 9;
                float a = 0.f;
                #pragma unroll
                for (int t9 = 0; t9 < 9; ++t9) {
                    const int dy = t9 / 3, dx = t9 - dy * 3;
                    a = fmaf(wd[t9], predw[j][hp + (dy - 1) * 18 + (dx - 1)], a);
                }
                qk[j][tid] = a;
            }
        }
        __syncthreads();

        // Phase C: Gram (thread t -> pair (d,e)) + squared norms, atomic into ws
        {
            const int d = tid >> 4, e = tid & 15;
            float acc = 0.f;
            #pragma unroll 8
            for (int p = 0; p < 256; ++p)
                acc = fmaf(qk[d][p], qk[16 + e][p], acc);
            float* gb = gram + ((b * NHEADS + n) * 288);
            atomicAdd(gb + tid, acc);          // G[d][e] at d*16+e == tid
            if (tid < 32) {
                float s = 0.f;
                #pragma unroll 8
                for (int p = 0; p < 256; ++p) {
                    const float v = qk[tid][p];
                    s = fmaf(v, v, s);
                }
                atomicAdd(gb + 256 + tid, s);  // qq at 256..271, kk at 272..287
            }
        }
        __syncthreads();
    }
}

// ---------------------------------------------------------------------------
// Attention kernel: per batch, logits = G/(||q||*||k||)*temp, softmax over e,
// then fold w_out: Mt[b][c=n*16+e][o] = sum_d w_out[o][n*16+d]*attn[n][d][e]
// ---------------------------------------------------------------------------
__global__ __launch_bounds__(256) void attn_kernel(
    const float* __restrict__ gram, const float* __restrict__ wout,
    const float* __restrict__ temp, float* __restrict__ Mt)
{
    __shared__ float attn_s[NHEADS][16][16];
    const int b = blockIdx.x;
    const int tid = threadIdx.x;

    if (tid < 64) {
        const int n = tid >> 4, d = tid & 15;
        const float* gb = gram + (b * NHEADS + n) * 288;
        const float nq = fmaxf(sqrtf(gb[256 + d]), 1e-12f);
        const float tn = temp[n];
        float lg[16];
        float mx = -3.4e38f;
        #pragma unroll
        for (int e = 0; e < 16; ++e) {
            const float nk = fmaxf(sqrtf(gb[272 + e]), 1e-12f);
            lg[e] = gb[d * 16 + e] / (nq * nk) * tn;
            mx = fmaxf(mx, lg[e]);
        }
        float s = 0.f;
        #pragma unroll
        for (int e = 0; e < 16; ++e) { lg[e] = expf(lg[e] - mx); s += lg[e]; }
        const float inv = 1.0f / s;
        #pragma unroll
        for (int e = 0; e < 16; ++e) attn_s[n][d][e] = lg[e] * inv;
    }
    __syncthreads();

    for (int idx = tid; idx < 4096; idx += 256) {
        const int c = idx >> 6;   // inner channel n*16+e
        const int o = idx & 63;
        const int n = c >> 4, e = c & 15;
        float acc = 0.f;
        #pragma unroll
        for (int d = 0; d < 16; ++d)
            acc = fmaf(wout[o * 64 + n * 16 + d], attn_s[n][d][e], acc);
        Mt[b * 4096 + idx] = acc;  // Mt[b][c][o], o contiguous -> coalesced
    }
}

// ---------------------------------------------------------------------------
// Pass 2: recompute v per tile (1x1 conv + dw 3x3), multiply illu, apply M.
// Each thread owns one pixel, y[64] accumulator in registers.
// ---------------------------------------------------------------------------
__global__ __launch_bounds__(256, 2) void pass2_kernel(
    const float* __restrict__ x, const float* __restrict__ illu,
    const float* __restrict__ wqkv, const float* __restrict__ wdw,
    const float* __restrict__ Mt, float* __restrict__ out)
{
    __shared__ float predw[32][328];

    const int bid = blockIdx.x;
    const int b = bid >> 8;
    const int tile = bid & 255;
    const int y0 = (tile >> 4) << 4;
    const int x0 = (tile & 15) << 4;
    const int tid = threadIdx.x;
    const int iy = tid >> 4, ix = tid & 15;
    const int pidx = (y0 + iy) * NW + (x0 + ix);

    float y[64];
    #pragma unroll
    for (int o = 0; o < 64; ++o) y[o] = 0.f;

    for (int cv = 0; cv < 2; ++cv) {       // 2 chunks of 32 v-channels
        if (cv) __syncthreads();           // predw readers of previous chunk done
        // Phase A: pre-dw v values over halo; x channels in 2 halves (reg pressure)
        for (int half = 0; half < 2; ++half) {
            for (int task = tid; task < 324; task += 256) {
                const int hy = task / 18;
                const int hx = task - hy * 18;
                const int py = y0 + hy - 1;
                const int px = x0 + hx - 1;
                const bool valid = (py >= 0) && (py < NH) && (px >= 0) && (px < NW);
                const float* xp = x + (size_t)b * (NC * NL) + py * NW + px
                                  + (size_t)(half * 32) * NL;
                float xr[32];
                #pragma unroll
                for (int c = 0; c < 32; ++c)
                    xr[c] = valid ? xp[(size_t)c * NL] : 0.0f;
                for (int j = 0; j < 32; ++j) {
                    const float* wv = wqkv + (128 + cv * 32 + j) * NC + half * 32;
                    float a = 0.f;
                    #pragma unroll
                    for (int c = 0; c < 32; ++c) a = fmaf(wv[c], xr[c], a);
                    if (half == 0) predw[j][task] = a;
                    else           predw[j][task] += a;
                }
            }
            // no sync between halves: same thread owns same tasks
        }
        __syncthreads();

        // Phase B: dw 3x3, * illu, y[o] += Mt[ci][o] * vi
        {
            const int hp = (iy + 1) * 18 + (ix + 1);
            for (int j = 0; j < 32; ++j) {
                const int ci = cv * 32 + j;      // inner channel
                const int ch = 128 + ci;         // dw weight channel (v block)
                const float* wd = wdw + ch * 9;
                float a = 0.f;
                #pragma unroll
                for (int t9 = 0; t9 < 9; ++t9) {
                    const int dy = t9 / 3, dx = t9 - dy * 3;
                    a = fmaf(wd[t9], predw[j][hp + (dy - 1) * 18 + (dx - 1)], a);
                }
                const float vi = a * illu[(size_t)(b * 64 + ci) * NL + pidx];
                const float* mrow = Mt + b * 4096 + ci * 64;  // uniform -> s_load
                #pragma unroll
                for (int o = 0; o < 64; ++o)
                    y[o] = fmaf(mrow[o], vi, y[o]);
            }
        }
    }

    // Epilogue: coalesced per-channel stores
    const size_t obase = (size_t)b * (64 * NL) + pidx;
    #pragma unroll
    for (int o = 0; o < 64; ++o)
        out[obase + (size_t)o * NL] = y[o];
}

extern "C" void kernel_launch(void* const* d_in, const int* in_sizes, int n_in,
                              void* d_out, int out_size, void* d_ws, size_t ws_size,
                              hipStream_t stream)
{
    const float* x    = (const float*)d_in[0];
    const float* illu = (const float*)d_in[1];
    const float* wqkv = (const float*)d_in[2];
    const float* wdw  = (const float*)d_in[3];
    const float* wout = (const float*)d_in[4];
    const float* temp = (const float*)d_in[5];
    float* out = (float*)d_out;
    float* ws  = (float*)d_ws;

    float* gram = ws;            // 4608 floats
    float* Mt   = ws + MT_OFF;   // 16384 floats

    hipMemsetAsync(gram, 0, GRAM_FLOATS * sizeof(float), stream);

    pass1_kernel<<<dim3(1024), dim3(256), 0, stream>>>(x, wqkv, wdw, gram);
    attn_kernel<<<dim3(4), dim3(256), 0, stream>>>(gram, wout, temp, Mt);
    pass2_kernel<<<dim3(1024), dim3(256), 0, stream>>>(x, illu, wqkv, wdw, Mt, out);
}